// Round 7
// baseline (2792.299 us; speedup 1.0000x reference)
//
#include <hip/hip_runtime.h>
#include <math.h>

#define T_ 512
#define B_ 64
#define H_ 512
#define D_ 32
#define G7H (7*H_)          // 3584
#define NBLK 128
#define NTHR 512
#define JPB 4               // hidden channels (j) per block -> 32 cols (4 pad)
#define BH (B_*H_)

typedef _Float16 f16x8 __attribute__((ext_vector_type(8)));
typedef float f32x4  __attribute__((ext_vector_type(4)));
typedef int   i32x2  __attribute__((ext_vector_type(2)));

// ---- P2[type][j][gate(8)] = b_gates + embed@W_x  (pad gate 7 = 0), exact f32 ----
__global__ void precompute_P2(const float* __restrict__ embed,
                              const float* __restrict__ Wg,
                              const float* __restrict__ bg,
                              float* __restrict__ P2) {
    int idx = blockIdx.x * blockDim.x + threadIdx.x;
    if (idx >= 33 * H_ * 8) return;
    int gate = idx & 7;
    int j    = (idx >> 3) & (H_ - 1);
    int type = idx >> 12;
    float acc = 0.f;
    if (gate < 7) {
        acc = bg[gate * H_ + j];
        #pragma unroll
        for (int d = 0; d < D_; ++d)
            acc += embed[type * D_ + d] * Wg[(size_t)d * G7H + gate * H_ + j];
    }
    P2[idx] = acc;
}

// ---- Wt16[n][k] = fp16(W_h^T) ----
__global__ void precompute_Wt16(const float* __restrict__ Wg,
                                _Float16* __restrict__ Wt) {
    int idx = blockIdx.x * blockDim.x + threadIdx.x;   // n*512 + k
    if (idx >= G7H * H_) return;
    int k = idx & (H_ - 1);
    int n = idx >> 9;
    Wt[idx] = (_Float16)Wg[(size_t)(D_ + k) * G7H + n];
}

// ---- h buffer 0 init (fp16) ----
__global__ void init_h16(const float* __restrict__ h0, _Float16* __restrict__ hf) {
    int idx = blockIdx.x * blockDim.x + threadIdx.x;
    if (idx >= BH) return;
    hf[idx] = (_Float16)h0[idx];
}

__device__ __forceinline__ float fast_rcp(float x) {
    float r;
    asm("v_rcp_f32 %0, %1" : "=v"(r) : "v"(x));
    return r;
}
__device__ __forceinline__ float fast_sigmoid(float x) {
    return fast_rcp(1.f + __expf(-x));
}
__device__ __forceinline__ float fast_tanh(float x) {
    return 1.f - 2.f * fast_rcp(1.f + __expf(2.f * x));
}

// one-time W loads: volatile asm so values CANNOT be rematerialized in-loop
#define LOADB(dst, p, OFF) \
    asm volatile("global_load_dwordx4 %0, %1, off offset:" #OFF \
                 : "=v"(dst) : "v"(p))
// per-step A loads (sc1 = L3-coherent)
#define LOADA(dst, p, OFF) \
    asm volatile("global_load_dwordx4 %0, %1, off offset:" #OFF " sc1" \
                 : "=v"(dst) : "v"(p) : "memory")

// ---------------- persistent recurrent kernel (fp16 MFMA) ----------------
__global__ void __launch_bounds__(NTHR, 1)
hawkes_main(const float* __restrict__ seq_dt, const int* __restrict__ seq_types,
            const float* __restrict__ c0, const float* __restrict__ ct0,
            const float* __restrict__ P2,
            const _Float16* __restrict__ Wt,
            _Float16* __restrict__ hf,     // 2 x (B_*H_) fp16 double buffer
            int* __restrict__ flags,       // NBLK ints, monotonic step counters
            float* __restrict__ out) {
    __shared__ f32x4 pcl[4][2][64];     // K-half partials: [wm][nt][lane] (8 KB)
    __shared__ float gl[B_][36];        // g recurrent part: [b][c_local] (9 KB)

    const int tid  = threadIdx.x;
    const int w    = tid >> 6;
    const int lane = tid & 63;
    const int wm   = w & 3;             // m-tile (b-range)
    const int kh   = w >> 2;            // K-half
    const int bid  = blockIdx.x;
    const int j0   = (bid & 7) * 64 + (bid >> 3) * JPB;   // XCD-grouped j
    const int m0   = wm * 16;

    // ---- one-time: W B-fragments pinned into registers via volatile asm ----
    // block cols: c_local = jl*8 + gate (gate 7 = pad), 32 cols = 2 n-tiles
    const int  krow = (lane >> 4) << 3;
    const bool pad  = (lane & 7) == 7;          // gate == 7
    const _Float16* wp0;
    const _Float16* wp1;
    {
        const int gate = lane & 7;
        const int jlA = ((lane & 15) >> 3);         // nt=0: jl 0..1
        const int jlB = 2 + ((lane & 15) >> 3);     // nt=1: jl 2..3
        wp0 = Wt + (pad ? 0 : (size_t)(gate * H_ + j0 + jlA) * (size_t)H_) + kh * 256 + krow;
        wp1 = Wt + (pad ? 0 : (size_t)(gate * H_ + j0 + jlB) * (size_t)H_) + kh * 256 + krow;
    }
    f16x8 Br[2][8];
    LOADB(Br[0][0], wp0, 0);   LOADB(Br[0][1], wp0, 64);
    LOADB(Br[0][2], wp0, 128); LOADB(Br[0][3], wp0, 192);
    LOADB(Br[0][4], wp0, 256); LOADB(Br[0][5], wp0, 320);
    LOADB(Br[0][6], wp0, 384); LOADB(Br[0][7], wp0, 448);
    LOADB(Br[1][0], wp1, 0);   LOADB(Br[1][1], wp1, 64);
    LOADB(Br[1][2], wp1, 128); LOADB(Br[1][3], wp1, 192);
    LOADB(Br[1][4], wp1, 256); LOADB(Br[1][5], wp1, 320);
    LOADB(Br[1][6], wp1, 384); LOADB(Br[1][7], wp1, 448);
    asm volatile("s_waitcnt vmcnt(0)" ::: "memory");
    f16x8 Bf[2][8];
    {
        const f16x8 zfrag = {0, 0, 0, 0, 0, 0, 0, 0};
        #pragma unroll
        for (int nt = 0; nt < 2; ++nt)
            #pragma unroll
            for (int kt = 0; kt < 8; ++kt)
                Bf[nt][kt] = pad ? zfrag : Br[nt][kt];
    }

    // ---- persistent cell state: tid<256 owns cell (b=tid>>2, jl=tid&3) ----
    const int eb = tid >> 2, ejl = tid & 3, ej = j0 + ejl;
    float c_s = 0.f, ct_s = 0.f;
    if (tid < 256) {
        c_s  = c0 [eb * H_ + ej];
        ct_s = ct0[eb * H_ + ej];
    }

    const size_t TBH = (size_t)T_ * BH;
    const int arow = m0 + (lane & 15);
    const int kb0  = kh * 256 + krow;

    for (int t = 0; t < T_; ++t) {
        // prefetch per-step scalars + P2 row (independent of flags; overlaps poll)
        int   type = 0; float dtv = 0.f;
        float4 pa = {0,0,0,0}, pb = {0,0,0,0};
        if (tid < 256) {
            type = seq_types[t * B_ + eb];
            dtv  = seq_dt  [t * B_ + eb];
            const float* pr = P2 + ((size_t)type * H_ + ej) * 8;
            pa = *(const float4*)pr;
            pb = *(const float4*)(pr + 4);
        }

        // ---- all-wave poll: every wave spins, then proceeds directly ----
        {
            const int* fp = flags + 2 * lane;
            int ok;
            do {
                i32x2 vv;
                asm volatile("global_load_dwordx2 %0, %1, off sc1\n\t"
                             "s_waitcnt vmcnt(0)"
                             : "=&v"(vv) : "v"(fp) : "memory");
                ok = (vv.x >= t) && (vv.y >= t);
            } while (!__all(ok));
        }

        // A-fragments: 8 pipelined 16B sc1 loads, one waitcnt
        const _Float16* ph = hf + (t & 1) * BH + arow * H_ + kb0;
        f16x8 Af[8];
        LOADA(Af[0], ph, 0);   LOADA(Af[1], ph, 64);
        LOADA(Af[2], ph, 128); LOADA(Af[3], ph, 192);
        LOADA(Af[4], ph, 256); LOADA(Af[5], ph, 320);
        LOADA(Af[6], ph, 384); LOADA(Af[7], ph, 448);
        asm volatile("s_waitcnt vmcnt(0)" ::: "memory");
        __builtin_amdgcn_sched_barrier(0);

        f32x4 acc0 = {0.f,0.f,0.f,0.f}, acc1 = {0.f,0.f,0.f,0.f};
        #pragma unroll
        for (int kt = 0; kt < 8; ++kt) {
            acc0 = __builtin_amdgcn_mfma_f32_16x16x32_f16(Af[kt], Bf[0][kt], acc0, 0, 0, 0);
            acc1 = __builtin_amdgcn_mfma_f32_16x16x32_f16(Af[kt], Bf[1][kt], acc1, 0, 0, 0);
        }

        // K-half combine: kh=1 publishes partials, kh=0 reduces
        if (kh == 1) { pcl[wm][0][lane] = acc0; pcl[wm][1][lane] = acc1; }
        __syncthreads();                                   // barrier #1

        if (kh == 0) {   // waves 0-3: reduce, deposit gl, elementwise (same wave!)
            f32x4 s0 = acc0 + pcl[wm][0][lane];
            f32x4 s1 = acc1 + pcl[wm][1][lane];
            const int col = lane & 15, rbase = m0 + ((lane >> 4) << 2);
            #pragma unroll
            for (int r = 0; r < 4; ++r) {
                gl[rbase + r][col]      = s0[r];
                gl[rbase + r][16 + col] = s1[r];
            }
            // gl written & read by THIS wave only: in-wave DS ordering suffices
            asm volatile("s_waitcnt lgkmcnt(0)" ::: "memory");
            __builtin_amdgcn_sched_barrier(0);

            float4 ga = *(const float4*)&gl[eb][ejl * 8];
            float4 gb = *(const float4*)&gl[eb][ejl * 8 + 4];
            const float g0 = ga.x + pa.x, g1 = ga.y + pa.y, g2 = ga.z + pa.z, g3 = ga.w + pa.w;
            const float g4 = gb.x + pb.x, g5 = gb.y + pb.y, g6 = gb.z + pb.z;

            const float inpt   = fast_sigmoid(g0);
            const float forget = fast_sigmoid(g1);
            const float outp   = fast_sigmoid(g2);
            const float in_tar = fast_sigmoid(g3);
            const float fg_tar = fast_sigmoid(g4);
            const float z      = fast_tanh(g5);
            const float y      = 10.f * g6;
            const float decay  = (fmaxf(y, 0.f) + __logf(1.f + __expf(-fabsf(y)))) * 0.1f;

            const float c_i      = forget * c_s + inpt * z;
            const float ctar_new = fg_tar * ct_s + in_tar * z;
            const float c_t = ctar_new + (c_i - ctar_new) * __expf(-decay * dtv);
            const float h_t = outp * fast_tanh(c_t);
            c_s  = c_t;
            ct_s = ctar_new;

            // recurrent h (fp16), pairwise u32 agent-scope stores
            union { _Float16 f; unsigned short u; } cv; cv.f = (_Float16)h_t;
            unsigned hs = cv.u;
            unsigned oh = (unsigned)__shfl_down((int)hs, 1);
            if ((ejl & 1) == 0) {
                unsigned* dh = (unsigned*)(hf + ((t + 1) & 1) * BH) + ((eb * H_ + ej) >> 1);
                __hip_atomic_store(dh, hs | (oh << 16), __ATOMIC_RELAXED, __HIP_MEMORY_SCOPE_AGENT);
            }

            // stash for out-stores after the publish barrier
            gl[eb][ejl * 8 + 0] = h_t;       // reuse gl as scratch (same wave)
            gl[eb][ejl * 8 + 1] = outp;
            gl[eb][ejl * 8 + 2] = c_i;
            gl[eb][ejl * 8 + 3] = ctar_new;
            gl[eb][ejl * 8 + 4] = decay;
        }

        // ---- publish: drain h stores (barrier emits vmcnt(0)), set flag ----
        __syncthreads();                                   // barrier #2
        if (tid == 0)
            __hip_atomic_store(flags + bid, t + 1, __ATOMIC_RELAXED, __HIP_MEMORY_SCOPE_AGENT);

        // ---- output stores overlap with next step's poll ----
        if (tid < 256) {
            const size_t base = (size_t)t * BH + (size_t)eb * H_ + ej;
            out[base]           = gl[eb][ejl * 8 + 0];
            out[TBH + base]     = gl[eb][ejl * 8 + 1];
            out[2 * TBH + base] = gl[eb][ejl * 8 + 2];
            out[3 * TBH + base] = gl[eb][ejl * 8 + 3];
            out[4 * TBH + base] = gl[eb][ejl * 8 + 4];
        }
    }
}

extern "C" void kernel_launch(void* const* d_in, const int* in_sizes, int n_in,
                              void* d_out, int out_size, void* d_ws, size_t ws_size,
                              hipStream_t stream) {
    const float* seq_dt    = (const float*)d_in[0];
    const int*   seq_types = (const int*)  d_in[1];
    const float* embed     = (const float*)d_in[2];
    const float* W_gates   = (const float*)d_in[3];
    const float* b_gates   = (const float*)d_in[4];
    const float* h0        = (const float*)d_in[5];
    const float* c0        = (const float*)d_in[6];
    const float* ct0       = (const float*)d_in[7];
    float* out = (float*)d_out;

    // workspace: P2 | Wt16 | hf(2 buf) | flags
    float* P2 = (float*)d_ws;                              // 33*512*8 f32
    _Float16* Wt = (_Float16*)(P2 + 33 * H_ * 8);          // 3584*512 fp16
    _Float16* hf = Wt + (size_t)G7H * H_;                  // 2*B*H fp16
    int* flags = (int*)(hf + 2 * BH);

    hipMemsetAsync(flags, 0, NBLK * sizeof(int), stream);
    {
        int total = 33 * H_ * 8;
        precompute_P2<<<(total + 255) / 256, 256, 0, stream>>>(embed, W_gates, b_gates, P2);
    }
    {
        int total = G7H * H_;
        precompute_Wt16<<<(total + 255) / 256, 256, 0, stream>>>(W_gates, Wt);
    }
    {
        int total = BH;
        init_h16<<<(total + 255) / 256, 256, 0, stream>>>(h0, hf);
    }
    {
        void* args[] = {(void*)&seq_dt, (void*)&seq_types, (void*)&c0, (void*)&ct0,
                        (void*)&P2, (void*)&Wt, (void*)&hf, (void*)&flags, (void*)&out};
        hipLaunchCooperativeKernel((void*)hawkes_main, dim3(NBLK), dim3(NTHR),
                                   args, 0, stream);
    }
}

// Round 8
// 2631.210 us; speedup vs baseline: 1.0612x; 1.0612x over previous
//
#include <hip/hip_runtime.h>
#include <math.h>

#define T_ 512
#define B_ 64
#define H_ 512
#define D_ 32
#define G7H (7*H_)          // 3584
#define NBLK 64
#define NTHR 512
#define JPB 8               // hidden channels (j) per block -> 64 cols (8 pad)
#define BH (B_*H_)

typedef _Float16 f16x8 __attribute__((ext_vector_type(8)));
typedef float f32x4  __attribute__((ext_vector_type(4)));

// ---- P2[type][j][gate(8)] = b_gates + embed@W_x  (pad gate 7 = 0), exact f32 ----
__global__ void precompute_P2(const float* __restrict__ embed,
                              const float* __restrict__ Wg,
                              const float* __restrict__ bg,
                              float* __restrict__ P2) {
    int idx = blockIdx.x * blockDim.x + threadIdx.x;
    if (idx >= 33 * H_ * 8) return;
    int gate = idx & 7;
    int j    = (idx >> 3) & (H_ - 1);
    int type = idx >> 12;
    float acc = 0.f;
    if (gate < 7) {
        acc = bg[gate * H_ + j];
        #pragma unroll
        for (int d = 0; d < D_; ++d)
            acc += embed[type * D_ + d] * Wg[(size_t)d * G7H + gate * H_ + j];
    }
    P2[idx] = acc;
}

// ---- Wt16[n][k] = fp16(W_h^T) ----
__global__ void precompute_Wt16(const float* __restrict__ Wg,
                                _Float16* __restrict__ Wt) {
    int idx = blockIdx.x * blockDim.x + threadIdx.x;   // n*512 + k
    if (idx >= G7H * H_) return;
    int k = idx & (H_ - 1);
    int n = idx >> 9;
    Wt[idx] = (_Float16)Wg[(size_t)(D_ + k) * G7H + n];
}

// ---- h buffer 0 init (fp16) ----
__global__ void init_h16(const float* __restrict__ h0, _Float16* __restrict__ hf) {
    int idx = blockIdx.x * blockDim.x + threadIdx.x;
    if (idx >= BH) return;
    hf[idx] = (_Float16)h0[idx];
}

__device__ __forceinline__ float fast_rcp(float x) {
    float r;
    asm("v_rcp_f32 %0, %1" : "=v"(r) : "v"(x));
    return r;
}
__device__ __forceinline__ float fast_sigmoid(float x) {
    return fast_rcp(1.f + __expf(-x));
}
__device__ __forceinline__ float fast_tanh(float x) {
    return 1.f - 2.f * fast_rcp(1.f + __expf(2.f * x));
}

// per-step A loads (sc1 = L3-coherent), pipelined 16B
#define LOADA(dst, p, OFF) \
    asm volatile("global_load_dwordx4 %0, %1, off offset:" #OFF " sc1" \
                 : "=v"(dst) : "v"(p) : "memory")

// ---------------- persistent recurrent kernel (fp16 MFMA) ----------------
__global__ void __launch_bounds__(NTHR, 1)
hawkes_main(const float* __restrict__ seq_dt, const int* __restrict__ seq_types,
            const float* __restrict__ c0, const float* __restrict__ ct0,
            const float* __restrict__ P2,
            const _Float16* __restrict__ Wt,
            _Float16* __restrict__ hf,     // 2 x (B_*H_) fp16 double buffer
            int* __restrict__ flags,       // NBLK ints, monotonic step counters
            float* __restrict__ out) {
    __shared__ f32x4 pcl[4][4][64];     // K-half partials: [wm][nt][lane] (16 KB)
    __shared__ float gl[B_][68];        // g recurrent part: [b][c_local] (17.4 KB)

    const int tid  = threadIdx.x;
    const int w    = tid >> 6;
    const int lane = tid & 63;
    const int wm   = w & 3;             // m-tile (b-range)
    const int kh   = w >> 2;            // K-half
    const int bid  = blockIdx.x;
    const int j0   = (bid & 7) * 64 + (bid >> 3) * JPB;   // XCD-grouped j
    const int m0   = wm * 16;
    const int krow = (lane >> 4) << 3;

    // ---- one-time: W fragments via plain loads; MFMA-only use -> AGPRs ----
    // block cols: c_local = jl*8 + gate (gate 7 = pad), 64 cols = 4 n-tiles
    f16x8 Bf[4][8];
    {
        const f16x8 zf = {0, 0, 0, 0, 0, 0, 0, 0};
        #pragma unroll
        for (int nt = 0; nt < 4; ++nt) {
            const int cl = nt * 16 + (lane & 15);
            const int gate = cl & 7, jl2 = cl >> 3;
            const bool pad = (gate == 7);
            const size_t nb = pad ? 0 : (size_t)(gate * H_ + j0 + jl2) * (size_t)H_;
            #pragma unroll
            for (int kt = 0; kt < 8; ++kt) {
                f16x8 v = *(const f16x8*)(Wt + nb + kh * 256 + kt * 32 + krow);
                Bf[nt][kt] = pad ? zf : v;
            }
        }
    }

    // ---- cell ownership: all 512 threads, exactly 1 cell each ----
    const int cb  = m0 + (lane & 15);          // batch row (== A-row of this lane)
    const int cjl = kh * 4 + (lane >> 4);      // local j
    const int cj  = j0 + cjl;
    float c_s  = c0 [cb * H_ + cj];
    float ct_s = ct0[cb * H_ + cj];

    // first-step scalars (prefetched; later iterations prefetch during poll)
    int   typ = seq_types[cb];
    float dtv = seq_dt[cb];
    float4 pa, pb;
    {
        const float* pr = P2 + ((size_t)typ * H_ + cj) * 8;
        pa = *(const float4*)pr;
        pb = *(const float4*)(pr + 4);
    }

    const size_t TBH = (size_t)T_ * BH;
    const int kb0 = kh * 256 + krow;

    for (int t = 0; t < T_; ++t) {
        // A-fragments: 8 pipelined 16B sc1 loads, one waitcnt
        const _Float16* ph = hf + (t & 1) * BH + cb * H_ + kb0;
        f16x8 Af[8];
        LOADA(Af[0], ph, 0);   LOADA(Af[1], ph, 64);
        LOADA(Af[2], ph, 128); LOADA(Af[3], ph, 192);
        LOADA(Af[4], ph, 256); LOADA(Af[5], ph, 320);
        LOADA(Af[6], ph, 384); LOADA(Af[7], ph, 448);
        asm volatile("s_waitcnt vmcnt(0)" ::: "memory");
        __builtin_amdgcn_sched_barrier(0);

        f32x4 a0 = {0.f,0.f,0.f,0.f}, a1 = {0.f,0.f,0.f,0.f};
        f32x4 a2 = {0.f,0.f,0.f,0.f}, a3 = {0.f,0.f,0.f,0.f};
        #pragma unroll
        for (int kt = 0; kt < 8; ++kt) {
            a0 = __builtin_amdgcn_mfma_f32_16x16x32_f16(Af[kt], Bf[0][kt], a0, 0, 0, 0);
            a1 = __builtin_amdgcn_mfma_f32_16x16x32_f16(Af[kt], Bf[1][kt], a1, 0, 0, 0);
            a2 = __builtin_amdgcn_mfma_f32_16x16x32_f16(Af[kt], Bf[2][kt], a2, 0, 0, 0);
            a3 = __builtin_amdgcn_mfma_f32_16x16x32_f16(Af[kt], Bf[3][kt], a3, 0, 0, 0);
        }

        // ---- symmetric K-half exchange: each side publishes the tiles the
        //      other side will finish; all 8 waves then reduce + elementwise ----
        if (kh == 0) { pcl[wm][2][lane] = a2; pcl[wm][3][lane] = a3; }
        else         { pcl[wm][0][lane] = a0; pcl[wm][1][lane] = a1; }
        asm volatile("s_waitcnt lgkmcnt(0)" ::: "memory");
        __builtin_amdgcn_sched_barrier(0);
        __builtin_amdgcn_s_barrier();                       // barrier #1 (LDS only)

        f32x4 sA, sB;
        if (kh == 0) { sA = a0 + pcl[wm][0][lane]; sB = a1 + pcl[wm][1][lane]; }
        else         { sA = a2 + pcl[wm][2][lane]; sB = a3 + pcl[wm][3][lane]; }

        // deposit into gl[b][c_local]; written & read by THIS wave only
        {
            const int col = lane & 15, rb2 = m0 + ((lane >> 4) << 2), cbs = kh * 32;
            #pragma unroll
            for (int r = 0; r < 4; ++r) {
                gl[rb2 + r][cbs + col]      = sA[r];
                gl[rb2 + r][cbs + 16 + col] = sB[r];
            }
        }
        asm volatile("s_waitcnt lgkmcnt(0)" ::: "memory");
        __builtin_amdgcn_sched_barrier(0);

        float4 ga = *(const float4*)&gl[cb][cjl * 8];
        float4 gb = *(const float4*)&gl[cb][cjl * 8 + 4];
        const float g0 = ga.x + pa.x, g1 = ga.y + pa.y, g2 = ga.z + pa.z, g3 = ga.w + pa.w;
        const float g4 = gb.x + pb.x, g5 = gb.y + pb.y, g6 = gb.z + pb.z;

        const float inpt   = fast_sigmoid(g0);
        const float forget = fast_sigmoid(g1);
        const float outp   = fast_sigmoid(g2);
        const float in_tar = fast_sigmoid(g3);
        const float fg_tar = fast_sigmoid(g4);
        const float z      = fast_tanh(g5);
        const float y      = 10.f * g6;
        const float decay  = (fmaxf(y, 0.f) + __logf(1.f + __expf(-fabsf(y)))) * 0.1f;

        const float c_i      = forget * c_s + inpt * z;
        const float ctar_new = fg_tar * ct_s + in_tar * z;
        const float c_t = ctar_new + (c_i - ctar_new) * __expf(-decay * dtv);
        const float h_t = outp * fast_tanh(c_t);
        c_s  = c_t;
        ct_s = ctar_new;

        // recurrent h (fp16): pair (cjl, cjl+1) -> one u32 agent-scope store
        {
            union { _Float16 f; unsigned short u; } cv; cv.f = (_Float16)h_t;
            unsigned hs = cv.u;
            unsigned oh = (unsigned)__shfl_down((int)hs, 16);
            if (((lane >> 4) & 1) == 0) {
                unsigned* dh = (unsigned*)(hf + ((t + 1) & 1) * BH) + ((cb * H_ + cj) >> 1);
                __hip_atomic_store(dh, hs | (oh << 16), __ATOMIC_RELAXED, __HIP_MEMORY_SCOPE_AGENT);
            }
        }
        asm volatile("s_waitcnt vmcnt(0)" ::: "memory");     // own h-store at L3
        __builtin_amdgcn_sched_barrier(0);
        __builtin_amdgcn_s_barrier();                        // barrier #2 (h published)
        if (tid == 0)
            __hip_atomic_store(flags + bid, t + 1, __ATOMIC_RELAXED, __HIP_MEMORY_SCOPE_AGENT);

        // ---- output stores: fire-and-forget, overlap the poll ----
        {
            const size_t base = (size_t)t * BH + (size_t)cb * H_ + cj;
            out[base]           = h_t;
            out[TBH + base]     = outp;
            out[2 * TBH + base] = c_i;
            out[3 * TBH + base] = ctar_new;
            out[4 * TBH + base] = decay;
        }

        // ---- prefetch next step's scalars + P2 row (overlaps poll) ----
        {
            const int tn = (t + 1 < T_) ? t + 1 : t;
            typ = seq_types[tn * B_ + cb];
            dtv = seq_dt  [tn * B_ + cb];
            const float* pr = P2 + ((size_t)typ * H_ + cj) * 8;
            pa = *(const float4*)pr;
            pb = *(const float4*)(pr + 4);
        }

        // ---- wave0 polls all 64 flags (1 per lane); raw-barrier release ----
        if (t + 1 < T_) {
            if (w == 0) {
                const int* fp = flags + lane;
                int ok;
                do {
                    int v;
                    asm volatile("global_load_dword %0, %1, off sc1\n\t"
                                 "s_waitcnt vmcnt(0)"
                                 : "=&v"(v) : "v"(fp) : "memory");
                    ok = v >= t + 1;
                } while (!__all(ok));
            }
            __builtin_amdgcn_sched_barrier(0);
            __builtin_amdgcn_s_barrier();                    // barrier #3 (release)
        }
    }
}

extern "C" void kernel_launch(void* const* d_in, const int* in_sizes, int n_in,
                              void* d_out, int out_size, void* d_ws, size_t ws_size,
                              hipStream_t stream) {
    const float* seq_dt    = (const float*)d_in[0];
    const int*   seq_types = (const int*)  d_in[1];
    const float* embed     = (const float*)d_in[2];
    const float* W_gates   = (const float*)d_in[3];
    const float* b_gates   = (const float*)d_in[4];
    const float* h0        = (const float*)d_in[5];
    const float* c0        = (const float*)d_in[6];
    const float* ct0       = (const float*)d_in[7];
    float* out = (float*)d_out;

    // workspace: P2 | Wt16 | hf(2 buf) | flags
    float* P2 = (float*)d_ws;                              // 33*512*8 f32
    _Float16* Wt = (_Float16*)(P2 + 33 * H_ * 8);          // 3584*512 fp16
    _Float16* hf = Wt + (size_t)G7H * H_;                  // 2*B*H fp16
    int* flags = (int*)(hf + 2 * BH);

    hipMemsetAsync(flags, 0, 256 * sizeof(int), stream);
    {
        int total = 33 * H_ * 8;
        precompute_P2<<<(total + 255) / 256, 256, 0, stream>>>(embed, W_gates, b_gates, P2);
    }
    {
        int total = G7H * H_;
        precompute_Wt16<<<(total + 255) / 256, 256, 0, stream>>>(W_gates, Wt);
    }
    {
        int total = BH;
        init_h16<<<(total + 255) / 256, 256, 0, stream>>>(h0, hf);
    }
    {
        void* args[] = {(void*)&seq_dt, (void*)&seq_types, (void*)&c0, (void*)&ct0,
                        (void*)&P2, (void*)&Wt, (void*)&hf, (void*)&flags, (void*)&out};
        hipLaunchCooperativeKernel((void*)hawkes_main, dim3(NBLK), dim3(NTHR),
                                   args, 0, stream);
    }
}

// Round 10
// 1907.705 us; speedup vs baseline: 1.4637x; 1.3793x over previous
//
#include <hip/hip_runtime.h>
#include <math.h>

#define T_ 512
#define B_ 64
#define H_ 512
#define D_ 32
#define G7H (7*H_)          // 3584
#define NBLK 128
#define NTHR 256            // 4 waves; wave = m-tile, FULL K per wave
#define JPB 4               // hidden channels (j) per block -> 32 cols (4 pad)
#define BH (B_*H_)

typedef _Float16 f16x8 __attribute__((ext_vector_type(8)));
typedef float f32x4  __attribute__((ext_vector_type(4)));
typedef int   i32x2  __attribute__((ext_vector_type(2)));

// ---- P2[type][j][gate(8)] = b_gates + embed@W_x  (pad gate 7 = 0), exact f32 ----
__global__ void precompute_P2(const float* __restrict__ embed,
                              const float* __restrict__ Wg,
                              const float* __restrict__ bg,
                              float* __restrict__ P2) {
    int idx = blockIdx.x * blockDim.x + threadIdx.x;
    if (idx >= 33 * H_ * 8) return;
    int gate = idx & 7;
    int j    = (idx >> 3) & (H_ - 1);
    int type = idx >> 12;
    float acc = 0.f;
    if (gate < 7) {
        acc = bg[gate * H_ + j];
        #pragma unroll
        for (int d = 0; d < D_; ++d)
            acc += embed[type * D_ + d] * Wg[(size_t)d * G7H + gate * H_ + j];
    }
    P2[idx] = acc;
}

// ---- Wt16[n][k] = fp16(W_h^T) ----
__global__ void precompute_Wt16(const float* __restrict__ Wg,
                                _Float16* __restrict__ Wt) {
    int idx = blockIdx.x * blockDim.x + threadIdx.x;   // n*512 + k
    if (idx >= G7H * H_) return;
    int k = idx & (H_ - 1);
    int n = idx >> 9;
    Wt[idx] = (_Float16)Wg[(size_t)(D_ + k) * G7H + n];
}

// ---- h buffer 0 init (fp16) ----
__global__ void init_h16(const float* __restrict__ h0, _Float16* __restrict__ hf) {
    int idx = blockIdx.x * blockDim.x + threadIdx.x;
    if (idx >= BH) return;
    hf[idx] = (_Float16)h0[idx];
}

__device__ __forceinline__ float fast_rcp(float x) {
    float r;
    asm("v_rcp_f32 %0, %1" : "=v"(r) : "v"(x));
    return r;
}
__device__ __forceinline__ float fast_sigmoid(float x) {
    return fast_rcp(1.f + __expf(-x));
}
__device__ __forceinline__ float fast_tanh(float x) {
    return 1.f - 2.f * fast_rcp(1.f + __expf(2.f * x));
}

// per-step A loads (sc1 = L3-coherent), pipelined 16B
#define LOADA(dst, p, OFF) \
    asm volatile("global_load_dwordx4 %0, %1, off offset:" #OFF " sc1" \
                 : "=v"(dst) : "v"(p) : "memory")

// ---------------- persistent recurrent kernel (fp16 MFMA, no K-split) ----------------
__global__ void __launch_bounds__(NTHR, 1)
hawkes_main(const float* __restrict__ seq_dt, const int* __restrict__ seq_types,
            const float* __restrict__ c0, const float* __restrict__ ct0,
            const float* __restrict__ P2,
            const _Float16* __restrict__ Wt,
            _Float16* __restrict__ hf,     // 2 x (B_*H_) fp16 double buffer
            int* __restrict__ flags,       // NBLK ints, monotonic step counters
            float* __restrict__ out) {
    __shared__ float gl[B_][36];        // in-wave g transpose only (9 KB)

    const int tid  = threadIdx.x;
    const int w    = tid >> 6;          // wave = m-tile (b-range), full K
    const int lane = tid & 63;
    const int bid  = blockIdx.x;
    const int j0   = (bid & 7) * 64 + (bid >> 3) * JPB;   // XCD-grouped j
    const int m0   = w * 16;
    const int krow = (lane >> 4) << 3;

    // ---- one-time: W fragments, plain loads, MFMA-only use (AGPR-friendly) ----
    // block cols: c_local = jl*8 + gate (gate 7 = pad), 32 cols = 2 n-tiles
    f16x8 Bf[2][16];
    {
        const f16x8 zf = {0, 0, 0, 0, 0, 0, 0, 0};
        #pragma unroll
        for (int nt = 0; nt < 2; ++nt) {
            const int cl = nt * 16 + (lane & 15);
            const int gate = cl & 7, jl2 = cl >> 3;
            const bool pad = (gate == 7);
            const size_t nb = pad ? 0 : (size_t)(gate * H_ + j0 + jl2) * (size_t)H_;
            #pragma unroll
            for (int kt = 0; kt < 16; ++kt) {
                f16x8 v = *(const f16x8*)(Wt + nb + kt * 32 + krow);
                Bf[nt][kt] = pad ? zf : v;
            }
        }
    }

    // ---- cell ownership: 256 threads, 1 cell each (b=tid>>2, jl=tid&3) ----
    const int eb = tid >> 2, ejl = tid & 3, ej = j0 + ejl;
    float c_s  = c0 [eb * H_ + ej];
    float ct_s = ct0[eb * H_ + ej];

    // first-step scalars (later steps prefetch during the poll window)
    int   typ = seq_types[eb];
    float dtv = seq_dt[eb];
    float4 pa, pb;
    {
        const float* pr = P2 + ((size_t)typ * H_ + ej) * 8;
        pa = *(const float4*)pr;
        pb = *(const float4*)(pr + 4);
    }

    const size_t TBH = (size_t)T_ * BH;
    const int arow = m0 + (lane & 15);

    for (int t = 0; t < T_; ++t) {
        // ---- A-fragments: 16 pipelined 16B sc1 loads (full K row slice) ----
        const _Float16* ph = hf + (t & 1) * BH + arow * H_ + krow;
        f16x8 Af[16];
        LOADA(Af[0],  ph, 0);    LOADA(Af[1],  ph, 64);
        LOADA(Af[2],  ph, 128);  LOADA(Af[3],  ph, 192);
        LOADA(Af[4],  ph, 256);  LOADA(Af[5],  ph, 320);
        LOADA(Af[6],  ph, 384);  LOADA(Af[7],  ph, 448);
        LOADA(Af[8],  ph, 512);  LOADA(Af[9],  ph, 576);
        LOADA(Af[10], ph, 640);  LOADA(Af[11], ph, 704);
        LOADA(Af[12], ph, 768);  LOADA(Af[13], ph, 832);
        LOADA(Af[14], ph, 896);  LOADA(Af[15], ph, 960);
        asm volatile("s_waitcnt vmcnt(0)" ::: "memory");
        __builtin_amdgcn_sched_barrier(0);

        f32x4 a0 = {0.f,0.f,0.f,0.f}, a1 = {0.f,0.f,0.f,0.f};
        #pragma unroll
        for (int kt = 0; kt < 16; ++kt) {
            a0 = __builtin_amdgcn_mfma_f32_16x16x32_f16(Af[kt], Bf[0][kt], a0, 0, 0, 0);
            a1 = __builtin_amdgcn_mfma_f32_16x16x32_f16(Af[kt], Bf[1][kt], a1, 0, 0, 0);
        }

        // ---- in-wave transpose via gl: writer wave == reader wave ----
        {
            const int col = lane & 15, rbase = m0 + ((lane >> 4) << 2);
            #pragma unroll
            for (int r = 0; r < 4; ++r) {
                gl[rbase + r][col]      = a0[r];
                gl[rbase + r][16 + col] = a1[r];
            }
        }
        asm volatile("s_waitcnt lgkmcnt(0)" ::: "memory");
        __builtin_amdgcn_sched_barrier(0);

        // ---- elementwise: 1 cell per thread ----
        float4 ga = *(const float4*)&gl[eb][ejl * 8];
        float4 gb = *(const float4*)&gl[eb][ejl * 8 + 4];
        const float g0 = ga.x + pa.x, g1 = ga.y + pa.y, g2 = ga.z + pa.z, g3 = ga.w + pa.w;
        const float g4 = gb.x + pb.x, g5 = gb.y + pb.y, g6 = gb.z + pb.z;

        const float inpt   = fast_sigmoid(g0);
        const float forget = fast_sigmoid(g1);
        const float outp   = fast_sigmoid(g2);
        const float in_tar = fast_sigmoid(g3);
        const float fg_tar = fast_sigmoid(g4);
        const float z      = fast_tanh(g5);
        const float y      = 10.f * g6;
        const float decay  = (fmaxf(y, 0.f) + __logf(1.f + __expf(-fabsf(y)))) * 0.1f;

        const float c_i      = forget * c_s + inpt * z;
        const float ctar_new = fg_tar * ct_s + in_tar * z;
        const float c_t = ctar_new + (c_i - ctar_new) * __expf(-decay * dtv);
        const float h_t = outp * fast_tanh(c_t);
        c_s  = c_t;
        ct_s = ctar_new;

        // ---- recurrent h (fp16), pairwise u32 agent-scope stores ----
        {
            union { _Float16 f; unsigned short u; } cv; cv.f = (_Float16)h_t;
            unsigned hs = cv.u;
            unsigned oh = (unsigned)__shfl_down((int)hs, 1);
            if ((ejl & 1) == 0) {
                unsigned* dh = (unsigned*)(hf + ((t + 1) & 1) * BH) + ((eb * H_ + ej) >> 1);
                __hip_atomic_store(dh, hs | (oh << 16), __ATOMIC_RELAXED, __HIP_MEMORY_SCOPE_AGENT);
            }
        }

        // ---- barrier #1: drain h stores (syncthreads emits vmcnt(0)), set flag ----
        __syncthreads();
        if (tid == 0)
            __hip_atomic_store(flags + bid, t + 1, __ATOMIC_RELAXED, __HIP_MEMORY_SCOPE_AGENT);

        // ---- output stores: fire-and-forget, overlap the poll ----
        {
            const size_t base = (size_t)t * BH + (size_t)eb * H_ + ej;
            out[base]           = h_t;
            out[TBH + base]     = outp;
            out[2 * TBH + base] = c_i;
            out[3 * TBH + base] = ctar_new;
            out[4 * TBH + base] = decay;
        }

        // ---- prefetch next step's scalars + P2 row (overlaps poll) ----
        {
            const int tn = (t + 1 < T_) ? t + 1 : t;
            typ = seq_types[tn * B_ + eb];
            dtv = seq_dt  [tn * B_ + eb];
            const float* pr = P2 + ((size_t)typ * H_ + ej) * 8;
            pa = *(const float4*)pr;
            pb = *(const float4*)(pr + 4);
        }

        // ---- wave0 polls all 128 flags; barrier #2 releases ----
        if (t + 1 < T_) {
            if (w == 0) {
                const int* fp = flags + 2 * lane;
                int ok;
                do {
                    i32x2 vv;
                    asm volatile("global_load_dwordx2 %0, %1, off sc1\n\t"
                                 "s_waitcnt vmcnt(0)"
                                 : "=&v"(vv) : "v"(fp) : "memory");
                    ok = (vv.x >= t + 1) && (vv.y >= t + 1);
                } while (!__all(ok));
            }
            __syncthreads();
        }
    }
}

extern "C" void kernel_launch(void* const* d_in, const int* in_sizes, int n_in,
                              void* d_out, int out_size, void* d_ws, size_t ws_size,
                              hipStream_t stream) {
    const float* seq_dt    = (const float*)d_in[0];
    const int*   seq_types = (const int*)  d_in[1];
    const float* embed     = (const float*)d_in[2];
    const float* W_gates   = (const float*)d_in[3];
    const float* b_gates   = (const float*)d_in[4];
    const float* h0        = (const float*)d_in[5];
    const float* c0        = (const float*)d_in[6];
    const float* ct0       = (const float*)d_in[7];
    float* out = (float*)d_out;

    // workspace: P2 | Wt16 | hf(2 buf) | flags
    float* P2 = (float*)d_ws;                              // 33*512*8 f32
    _Float16* Wt = (_Float16*)(P2 + 33 * H_ * 8);          // 3584*512 fp16
    _Float16* hf = Wt + (size_t)G7H * H_;                  // 2*B*H fp16
    int* flags = (int*)(hf + 2 * BH);

    hipMemsetAsync(flags, 0, NBLK * sizeof(int), stream);
    {
        int total = 33 * H_ * 8;
        precompute_P2<<<(total + 255) / 256, 256, 0, stream>>>(embed, W_gates, b_gates, P2);
    }
    {
        int total = G7H * H_;
        precompute_Wt16<<<(total + 255) / 256, 256, 0, stream>>>(W_gates, Wt);
    }
    {
        int total = BH;
        init_h16<<<(total + 255) / 256, 256, 0, stream>>>(h0, hf);
    }
    {
        void* args[] = {(void*)&seq_dt, (void*)&seq_types, (void*)&c0, (void*)&ct0,
                        (void*)&P2, (void*)&Wt, (void*)&hf, (void*)&flags, (void*)&out};
        hipLaunchCooperativeKernel((void*)hawkes_main, dim3(NBLK), dim3(NTHR),
                                   args, 0, stream);
    }
}